// Round 14
// baseline (941.704 us; speedup 1.0000x reference)
//
#include <hip/hip_runtime.h>
#include <math.h>

// OnlineLabelSmoothing: B=16384 rows, C=4096 classes, f32.
// out = [loss(1), update(C*C), idx_count(C)] f32.
// Round 14 = r11 (proven 191us) + fused finalize (r13-verified) only.
// r13 lesson: __builtin_nontemporal_load KILLS bulk load issue (VGPR 64->24,
// serialized chain, 820us). All hot-stream loads are plain float4 again.
// NT retained ONLY for the write-once upd zeroing store.

constexpr int CC    = 4096;
constexpr int WAVE  = 64;
constexpr int WPB   = 4;               // waves per block
constexpr int TPB   = 256;
constexpr int CHUNK = CC / WPB;        // 1024 elems per wave
constexpr int JPW   = CHUNK / (WAVE * 4);  // float4 per lane per chunk = 4
constexpr float ALPHA_V = 0.5f;
constexpr int ACC_SLOTS = 64;          // 64 slots x {hard,soft} doubles

__device__ inline void amax2(float v, int i, float& bv, int& bi) {
  // first-occurrence argmax: prefer smaller index on exact tie
  if (v > bv || (v == bv && i < bi)) { bv = v; bi = i; }
}

__device__ inline void wave_argmax(float& lv, int& li) {
  #pragma unroll
  for (int o = 1; o < WAVE; o <<= 1) {
    float ov = __shfl_xor(lv, o, WAVE);
    int   oi = __shfl_xor(li, o, WAVE);
    amax2(ov, oi, lv, li);
  }
}

__device__ inline float wave_sum(float v) {
  #pragma unroll
  for (int o = 1; o < WAVE; o <<= 1) v += __shfl_xor(v, o, WAVE);
  return v;
}

// ---- mega: even blocks transpose(+zeroing), odd blocks per-row y argmax ----
__global__ void ols_mega(const float* __restrict__ sup,
                         float* __restrict__ supT,
                         float* __restrict__ upd,
                         float* __restrict__ cnt,
                         double* __restrict__ acc,
                         unsigned* __restrict__ done,
                         const float* __restrict__ y,
                         int* __restrict__ labels, int C) {
  __shared__ float tile[32][33];
  __shared__ float s_m[WPB];
  __shared__ int   s_i[WPB];
  const int blk = blockIdx.x;
  const int tid = threadIdx.x;
  if ((blk & 1) == 0) {
    // ---- transpose tile (32x32), threads decoded as (32,8) ----
    const int t2 = blk >> 1;
    const int bx = (t2 & 127) * 32, by = (t2 >> 7) * 32;
    const int tx = tid & 31, ty = tid >> 5;
    if (by == 0 && ty == 0) cnt[bx + tx] = 0.0f;
    if (t2 == 0) {
      if (tid < ACC_SLOTS * 2) acc[tid] = 0.0;
      if (tid == 0) *done = 0u;
    }
    #pragma unroll
    for (int j = 0; j < 32; j += 8)
      tile[ty + j][tx] = sup[(size_t)(by + ty + j) * C + bx + tx];
    __syncthreads();
    #pragma unroll
    for (int j = 0; j < 32; j += 8) {
      const size_t o = (size_t)(bx + ty + j) * C + by + tx;
      supT[o] = tile[tx][ty + j];                    // cached: re-read by ols_row
      __builtin_nontemporal_store(0.0f, &upd[o]);   // write-once zero
    }
  } else {
    // ---- per-row y argmax: wave wv handles chunk wv ----
    const int wv = tid >> 6, lane = tid & 63;
    const int b = blk >> 1;
    const float4* p = reinterpret_cast<const float4*>(y + (size_t)b * CC)
                      + wv * (CHUNK / 4);
    float4 v[JPW];
    #pragma unroll
    for (int j = 0; j < JPW; ++j) v[j] = p[j * WAVE + lane];

    float m = -INFINITY; int mi = 0x7fffffff;
    #pragma unroll
    for (int j = 0; j < JPW; ++j) {
      const int base = wv * CHUNK + (j * WAVE + lane) * 4;
      amax2(v[j].x, base + 0, m, mi);
      amax2(v[j].y, base + 1, m, mi);
      amax2(v[j].z, base + 2, m, mi);
      amax2(v[j].w, base + 3, m, mi);
    }
    wave_argmax(m, mi);
    if (lane == 0) { s_m[wv] = m; s_i[wv] = mi; }
    __syncthreads();
    if (tid == 0) {
      float bm = s_m[0]; int bi = s_i[0];
      amax2(s_m[1], s_i[1], bm, bi);
      amax2(s_m[2], s_i[2], bm, bi);
      amax2(s_m[3], s_i[3], bm, bi);
      labels[b] = bi;
    }
  }
}

// ---- ols_row: block per row; stream y_h + supT[lab]; losses + scatter;
//      last block folds acc -> out[0] (finalize fused) ----
__global__ void ols_row(const float* __restrict__ y_h,
                        const int* __restrict__ labels,
                        const float* __restrict__ supT,
                        float* __restrict__ upd, float* __restrict__ cnt,
                        double* __restrict__ acc,
                        unsigned* __restrict__ done,
                        float* __restrict__ out0, double invB) {
  __shared__ float s_m[WPB], s_se[WPB], s_W[WPB], s_WX[WPB];
  __shared__ int   s_mi[WPB];
  __shared__ int   s_last;
  const int tid = threadIdx.x;
  const int wv = tid >> 6, lane = tid & 63;
  const int b = blockIdx.x;
  const int lab = labels[b];
  const size_t roff = (size_t)b * CC;

  const float4* px = reinterpret_cast<const float4*>(y_h + roff) + wv * (CHUNK / 4);
  const float4* pw = reinterpret_cast<const float4*>(supT + (size_t)lab * CC)
                     + wv * (CHUNK / 4);

  // r9/r11-proven inner structure: bulk plain-float4 loads, single fused pass
  float4 xv[JPW], wv4[JPW];
  #pragma unroll
  for (int j = 0; j < JPW; ++j) xv[j] = px[j * WAVE + lane];
  #pragma unroll
  for (int j = 0; j < JPW; ++j) wv4[j] = pw[j * WAVE + lane];

  float m = -INFINITY; int mi = 0x7fffffff;
  float se = 0.f, W = 0.f, WX = 0.f;
  #pragma unroll
  for (int j = 0; j < JPW; ++j) {
    const int base = wv * CHUNK + (j * WAVE + lane) * 4;
    amax2(xv[j].x, base + 0, m, mi);
    amax2(xv[j].y, base + 1, m, mi);
    amax2(xv[j].z, base + 2, m, mi);
    amax2(xv[j].w, base + 3, m, mi);
    se += __expf(xv[j].x) + __expf(xv[j].y) + __expf(xv[j].z) + __expf(xv[j].w);
    W  += wv4[j].x + wv4[j].y + wv4[j].z + wv4[j].w;
    WX += wv4[j].x * xv[j].x + wv4[j].y * xv[j].y
        + wv4[j].z * xv[j].z + wv4[j].w * xv[j].w;
  }
  wave_argmax(m, mi);
  se = wave_sum(se);
  W  = wave_sum(W);
  WX = wave_sum(WX);
  if (lane == 0) {
    s_m[wv] = m; s_mi[wv] = mi; s_se[wv] = se; s_W[wv] = W; s_WX[wv] = WX;
  }
  __syncthreads();

  // block reduce (all threads; block-uniform results)
  float pm = s_m[0]; int pred = s_mi[0];
  amax2(s_m[1], s_mi[1], pm, pred);
  amax2(s_m[2], s_mi[2], pm, pred);
  amax2(s_m[3], s_mi[3], pm, pred);
  const float Z   = s_se[0] + s_se[1] + s_se[2] + s_se[3];
  const float Wt  = s_W[0] + s_W[1] + s_W[2] + s_W[3];
  const float WXt = s_WX[0] + s_WX[1] + s_WX[2] + s_WX[3];
  const float logZ = __logf(Z);

  if (tid == 0) {
    const float xl = y_h[roff + lab];          // L2-hot (this block read the row)
    const int slot = (b & (ACC_SLOTS - 1)) * 2;
    atomicAdd(&acc[slot + 0], (double)(logZ - xl));        // hard
    atomicAdd(&acc[slot + 1], (double)(logZ * Wt - WXt));  // soft
    if (pred == lab) atomicAdd(&cnt[pred], 1.0f);
  }

  // rare, block-uniform: scatter probs into update column `pred`
  if (pred == lab) {
    const float invZ = 1.0f / Z;
    const float4* pr = reinterpret_cast<const float4*>(y_h + roff);
    #pragma unroll
    for (int j = 0; j < 4; ++j) {
      const int i4 = j * TPB + tid;
      const float4 q = pr[i4];                 // L2-hot re-read
      const int base = i4 * 4;
      atomicAdd(&upd[(size_t)(base + 0) * CC + pred], __expf(q.x) * invZ);
      atomicAdd(&upd[(size_t)(base + 1) * CC + pred], __expf(q.y) * invZ);
      atomicAdd(&upd[(size_t)(base + 2) * CC + pred], __expf(q.z) * invZ);
      atomicAdd(&upd[(size_t)(base + 3) * CC + pred], __expf(q.w) * invZ);
    }
  }

  // ---- fused finalize: last block folds acc (device-scope) ----
  if (tid == 0) {
    __threadfence();                                  // acc/upd visible
    const unsigned prev = atomicAdd(done, 1u);
    s_last = (prev == (unsigned)gridDim.x - 1) ? 1 : 0;
  }
  __syncthreads();
  if (s_last && tid < ACC_SLOTS) {
    double h = atomicAdd(&acc[tid * 2 + 0], 0.0);     // coherent read
    double s = atomicAdd(&acc[tid * 2 + 1], 0.0);
    #pragma unroll
    for (int o = 1; o < WAVE; o <<= 1) {
      h += __shfl_xor(h, o, WAVE);
      s += __shfl_xor(s, o, WAVE);
    }
    if (tid == 0)
      out0[0] = (float)(((double)ALPHA_V * h + (1.0 - (double)ALPHA_V) * s) * invB);
  }
}

// ---- fallback (tiny ws): fused per-row kernel, direct sup column reads ----
__global__ void ols_fallback(const float* __restrict__ y_h, const float* __restrict__ y,
                             const float* __restrict__ sup,
                             float* __restrict__ upd, float* __restrict__ cnt,
                             double* __restrict__ acc) {
  const int wv = threadIdx.x >> 6, lane = threadIdx.x & 63;
  const int b = blockIdx.x * WPB + wv;
  const size_t roff = (size_t)b * CC;
  const float4* y4 = reinterpret_cast<const float4*>(y + roff);
  const float4* x4 = reinterpret_cast<const float4*>(y_h + roff);
  const int K16 = CC / (WAVE * 4);

  float lv = -INFINITY; int li = 0x7fffffff;
  for (int k = 0; k < K16; ++k) {
    const float4 v = y4[k * WAVE + lane];
    const int base = (k * WAVE + lane) * 4;
    amax2(v.x, base + 0, lv, li); amax2(v.y, base + 1, lv, li);
    amax2(v.z, base + 2, lv, li); amax2(v.w, base + 3, lv, li);
  }
  wave_argmax(lv, li);
  const int lab = li;
  const float xl = y_h[roff + lab];

  float m = -INFINITY; int mi = 0x7fffffff;
  float se = 0.f, W = 0.f, WX = 0.f;
  for (int k = 0; k < K16; ++k) {
    const float4 xv = x4[k * WAVE + lane];
    const int base = (k * WAVE + lane) * 4;
    const float w0 = sup[(size_t)(base + 0) * CC + lab];
    const float w1 = sup[(size_t)(base + 1) * CC + lab];
    const float w2 = sup[(size_t)(base + 2) * CC + lab];
    const float w3 = sup[(size_t)(base + 3) * CC + lab];
    amax2(xv.x, base + 0, m, mi); amax2(xv.y, base + 1, m, mi);
    amax2(xv.z, base + 2, m, mi); amax2(xv.w, base + 3, m, mi);
    se += __expf(xv.x) + __expf(xv.y) + __expf(xv.z) + __expf(xv.w);
    W  += w0 + w1 + w2 + w3;
    WX += w0 * xv.x + w1 * xv.y + w2 * xv.z + w3 * xv.w;
  }
  wave_argmax(m, mi);
  const int pred = mi;
  const float Z = wave_sum(se), Wt = wave_sum(W), WXt = wave_sum(WX);
  const float logZ = __logf(Z);
  if (pred == lab) {
    const float invZ = 1.0f / Z;
    for (int k = 0; k < K16; ++k) {
      const float4 xv = x4[k * WAVE + lane];
      const int base = (k * WAVE + lane) * 4;
      atomicAdd(&upd[(size_t)(base + 0) * CC + pred], __expf(xv.x) * invZ);
      atomicAdd(&upd[(size_t)(base + 1) * CC + pred], __expf(xv.y) * invZ);
      atomicAdd(&upd[(size_t)(base + 2) * CC + pred], __expf(xv.z) * invZ);
      atomicAdd(&upd[(size_t)(base + 3) * CC + pred], __expf(xv.w) * invZ);
    }
    if (lane == 0) atomicAdd(&cnt[pred], 1.0f);
  }
  if (lane == 0) {
    const int slot = (b & (ACC_SLOTS - 1)) * 2;
    atomicAdd(&acc[slot + 0], (double)(logZ - xl));
    atomicAdd(&acc[slot + 1], (double)(logZ * Wt - WXt));
  }
}

__global__ void ols_finalize(const double* __restrict__ acc,
                             float* __restrict__ out, double invB) {
  double h = 0.0, s = 0.0;
  for (int i = 0; i < ACC_SLOTS; ++i) { h += acc[i * 2]; s += acc[i * 2 + 1]; }
  out[0] = (float)(((double)ALPHA_V * h + (1.0 - (double)ALPHA_V) * s) * invB);
}

extern "C" void kernel_launch(void* const* d_in, const int* in_sizes, int n_in,
                              void* d_out, int out_size, void* d_ws, size_t ws_size,
                              hipStream_t stream) {
  const float* y_h = (const float*)d_in[0];
  const float* y   = (const float*)d_in[1];
  const float* sup = (const float*)d_in[2];
  const int C = CC;                       // 4096 (supervise is C*C)
  const int B = in_sizes[0] / C;          // 16384

  float* out        = (float*)d_out;
  float* out_update = out + 1;
  float* out_count  = out + 1 + (size_t)C * C;

  // ws layout: acc @0 (1KB) | done @2048 | labels @4096 (64KB) | supT @69632
  char* ws = (char*)d_ws;
  double*   acc    = (double*)ws;
  unsigned* done   = (unsigned*)(ws + 2048);
  int*      labels = (int*)(ws + 4096);
  float*    supT   = (float*)(ws + 4096 + 65536);
  const size_t need = 4096 + 65536 + (size_t)C * C * sizeof(float);

  if (ws_size >= need) {
    // even blocks: (C/32)^2 = 16384 transpose tiles; odd: 16384 rows
    ols_mega<<<32768, TPB, 0, stream>>>(sup, supT, out_update, out_count,
                                        acc, done, y, labels, C);
    ols_row<<<B, TPB, 0, stream>>>(y_h, labels, supT,
                                   out_update, out_count, acc, done,
                                   out, 1.0 / (double)B);
  } else {
    hipMemsetAsync(d_out, 0, (size_t)out_size * sizeof(float), stream);
    hipMemsetAsync(d_ws, 0, 4096, stream);
    ols_fallback<<<B / WPB, TPB, 0, stream>>>(y_h, y, sup,
                                              out_update, out_count, acc);
    ols_finalize<<<1, 1, 0, stream>>>(acc, out, 1.0 / (double)B);
  }
}

// Round 15
// 188.083 us; speedup vs baseline: 5.0068x; 5.0068x over previous
//
#include <hip/hip_runtime.h>
#include <math.h>

// OnlineLabelSmoothing: B=16384 rows, C=4096 classes, f32.
// out = [loss(1), update(C*C), idx_count(C)] f32.
// Round 15: EXACT revert to round 11 (measured 191us, best verified).
// r13/r14 lesson: the fused-finalize epilogue (done-counter + double
// shuffle) flips hipcc's occupancy heuristic -> VGPR 64->24, bulk loads
// serialized, 4.3x regression. NT loads were a misattribution (r14
// proved it). Keep the proven 3-kernel structure, plain float4 loads,
// separate trivial finalize.

constexpr int CC    = 4096;
constexpr int WAVE  = 64;
constexpr int WPB   = 4;               // waves per block
constexpr int TPB   = 256;
constexpr int CHUNK = CC / WPB;        // 1024 elems per wave
constexpr int JPW   = CHUNK / (WAVE * 4);  // float4 per lane per chunk = 4
constexpr float ALPHA_V = 0.5f;
constexpr int ACC_SLOTS = 64;

__device__ inline void amax2(float v, int i, float& bv, int& bi) {
  // first-occurrence argmax: prefer smaller index on exact tie
  if (v > bv || (v == bv && i < bi)) { bv = v; bi = i; }
}

__device__ inline void wave_argmax(float& lv, int& li) {
  #pragma unroll
  for (int o = 1; o < WAVE; o <<= 1) {
    float ov = __shfl_xor(lv, o, WAVE);
    int   oi = __shfl_xor(li, o, WAVE);
    amax2(ov, oi, lv, li);
  }
}

__device__ inline float wave_sum(float v) {
  #pragma unroll
  for (int o = 1; o < WAVE; o <<= 1) v += __shfl_xor(v, o, WAVE);
  return v;
}

// ---- mega: even blocks transpose(+zeroing), odd blocks per-row y argmax ----
__global__ void ols_mega(const float* __restrict__ sup,
                         float* __restrict__ supT,
                         float* __restrict__ upd,
                         float* __restrict__ cnt,
                         double* __restrict__ acc,
                         const float* __restrict__ y,
                         int* __restrict__ labels, int C) {
  __shared__ float tile[32][33];
  __shared__ float s_m[WPB];
  __shared__ int   s_i[WPB];
  const int blk = blockIdx.x;
  const int tid = threadIdx.x;
  if ((blk & 1) == 0) {
    // ---- transpose tile (32x32), threads decoded as (32,8) ----
    const int t2 = blk >> 1;
    const int bx = (t2 & 127) * 32, by = (t2 >> 7) * 32;
    const int tx = tid & 31, ty = tid >> 5;
    if (by == 0 && ty == 0) cnt[bx + tx] = 0.0f;
    if (t2 == 0 && tid < ACC_SLOTS * 2) acc[tid] = 0.0;
    #pragma unroll
    for (int j = 0; j < 32; j += 8)
      tile[ty + j][tx] = sup[(size_t)(by + ty + j) * C + bx + tx];
    __syncthreads();
    #pragma unroll
    for (int j = 0; j < 32; j += 8) {
      const size_t o = (size_t)(bx + ty + j) * C + by + tx;
      supT[o] = tile[tx][ty + j];
      upd[o]  = 0.0f;
    }
  } else {
    // ---- per-row y argmax: wave wv handles chunk wv ----
    const int wv = tid >> 6, lane = tid & 63;
    const int b = blk >> 1;
    const float4* p = reinterpret_cast<const float4*>(y + (size_t)b * CC)
                      + wv * (CHUNK / 4);
    float4 v[JPW];
    #pragma unroll
    for (int j = 0; j < JPW; ++j) v[j] = p[j * WAVE + lane];

    float m = -INFINITY; int mi = 0x7fffffff;
    #pragma unroll
    for (int j = 0; j < JPW; ++j) {
      const int base = wv * CHUNK + (j * WAVE + lane) * 4;
      amax2(v[j].x, base + 0, m, mi);
      amax2(v[j].y, base + 1, m, mi);
      amax2(v[j].z, base + 2, m, mi);
      amax2(v[j].w, base + 3, m, mi);
    }
    wave_argmax(m, mi);
    if (lane == 0) { s_m[wv] = m; s_i[wv] = mi; }
    __syncthreads();
    if (tid == 0) {
      float bm = s_m[0]; int bi = s_i[0];
      amax2(s_m[1], s_i[1], bm, bi);
      amax2(s_m[2], s_i[2], bm, bi);
      amax2(s_m[3], s_i[3], bm, bi);
      labels[b] = bi;
    }
  }
}

// ---- ols_row: block per row; stream y_h + supT[lab]; losses + scatter ----
__global__ void ols_row(const float* __restrict__ y_h,
                        const int* __restrict__ labels,
                        const float* __restrict__ supT,
                        float* __restrict__ upd, float* __restrict__ cnt,
                        double* __restrict__ acc) {
  __shared__ float s_m[WPB], s_se[WPB], s_W[WPB], s_WX[WPB];
  __shared__ int   s_mi[WPB];
  const int tid = threadIdx.x;
  const int wv = tid >> 6, lane = tid & 63;
  const int b = blockIdx.x;
  const int lab = labels[b];
  const size_t roff = (size_t)b * CC;

  const float4* px = reinterpret_cast<const float4*>(y_h + roff) + wv * (CHUNK / 4);
  const float4* pw = reinterpret_cast<const float4*>(supT + (size_t)lab * CC)
                     + wv * (CHUNK / 4);

  // r9-proven inner structure: bulk loads, single fused pass
  float4 xv[JPW], wv4[JPW];
  #pragma unroll
  for (int j = 0; j < JPW; ++j) xv[j] = px[j * WAVE + lane];
  #pragma unroll
  for (int j = 0; j < JPW; ++j) wv4[j] = pw[j * WAVE + lane];

  float m = -INFINITY; int mi = 0x7fffffff;
  float se = 0.f, W = 0.f, WX = 0.f;
  #pragma unroll
  for (int j = 0; j < JPW; ++j) {
    const int base = wv * CHUNK + (j * WAVE + lane) * 4;
    amax2(xv[j].x, base + 0, m, mi);
    amax2(xv[j].y, base + 1, m, mi);
    amax2(xv[j].z, base + 2, m, mi);
    amax2(xv[j].w, base + 3, m, mi);
    se += __expf(xv[j].x) + __expf(xv[j].y) + __expf(xv[j].z) + __expf(xv[j].w);
    W  += wv4[j].x + wv4[j].y + wv4[j].z + wv4[j].w;
    WX += wv4[j].x * xv[j].x + wv4[j].y * xv[j].y
        + wv4[j].z * xv[j].z + wv4[j].w * xv[j].w;
  }
  wave_argmax(m, mi);
  se = wave_sum(se);
  W  = wave_sum(W);
  WX = wave_sum(WX);
  if (lane == 0) {
    s_m[wv] = m; s_mi[wv] = mi; s_se[wv] = se; s_W[wv] = W; s_WX[wv] = WX;
  }
  __syncthreads();

  // block reduce (all threads; block-uniform results)
  float pm = s_m[0]; int pred = s_mi[0];
  amax2(s_m[1], s_mi[1], pm, pred);
  amax2(s_m[2], s_mi[2], pm, pred);
  amax2(s_m[3], s_mi[3], pm, pred);
  const float Z   = s_se[0] + s_se[1] + s_se[2] + s_se[3];
  const float Wt  = s_W[0] + s_W[1] + s_W[2] + s_W[3];
  const float WXt = s_WX[0] + s_WX[1] + s_WX[2] + s_WX[3];
  const float logZ = __logf(Z);

  if (tid == 0) {
    const float xl = y_h[roff + lab];          // L2-hot (this block read the row)
    const int slot = (b & (ACC_SLOTS - 1)) * 2;
    atomicAdd(&acc[slot + 0], (double)(logZ - xl));        // hard
    atomicAdd(&acc[slot + 1], (double)(logZ * Wt - WXt));  // soft
    if (pred == lab) atomicAdd(&cnt[pred], 1.0f);
  }

  // rare, block-uniform: scatter probs into update column `pred`
  if (pred == lab) {
    const float invZ = 1.0f / Z;
    const float4* pr = reinterpret_cast<const float4*>(y_h + roff);
    #pragma unroll
    for (int j = 0; j < 4; ++j) {
      const int i4 = j * TPB + tid;
      const float4 q = pr[i4];                 // L2-hot re-read
      const int base = i4 * 4;
      atomicAdd(&upd[(size_t)(base + 0) * CC + pred], __expf(q.x) * invZ);
      atomicAdd(&upd[(size_t)(base + 1) * CC + pred], __expf(q.y) * invZ);
      atomicAdd(&upd[(size_t)(base + 2) * CC + pred], __expf(q.z) * invZ);
      atomicAdd(&upd[(size_t)(base + 3) * CC + pred], __expf(q.w) * invZ);
    }
  }
}

__global__ void ols_finalize(const double* __restrict__ acc,
                             float* __restrict__ out, double invB) {
  double h = 0.0, s = 0.0;
  for (int i = 0; i < ACC_SLOTS; ++i) { h += acc[i * 2]; s += acc[i * 2 + 1]; }
  out[0] = (float)(((double)ALPHA_V * h + (1.0 - (double)ALPHA_V) * s) * invB);
}

// ---- fallback (tiny ws): fused per-row kernel, direct sup column reads ----
__global__ void ols_fallback(const float* __restrict__ y_h, const float* __restrict__ y,
                             const float* __restrict__ sup,
                             float* __restrict__ upd, float* __restrict__ cnt,
                             double* __restrict__ acc) {
  const int wv = threadIdx.x >> 6, lane = threadIdx.x & 63;
  const int b = blockIdx.x * WPB + wv;
  const size_t roff = (size_t)b * CC;
  const float4* y4 = reinterpret_cast<const float4*>(y + roff);
  const float4* x4 = reinterpret_cast<const float4*>(y_h + roff);
  const int K16 = CC / (WAVE * 4);

  float lv = -INFINITY; int li = 0x7fffffff;
  for (int k = 0; k < K16; ++k) {
    const float4 v = y4[k * WAVE + lane];
    const int base = (k * WAVE + lane) * 4;
    amax2(v.x, base + 0, lv, li); amax2(v.y, base + 1, lv, li);
    amax2(v.z, base + 2, lv, li); amax2(v.w, base + 3, lv, li);
  }
  wave_argmax(lv, li);
  const int lab = li;
  const float xl = y_h[roff + lab];

  float m = -INFINITY; int mi = 0x7fffffff;
  float se = 0.f, W = 0.f, WX = 0.f;
  for (int k = 0; k < K16; ++k) {
    const float4 xv = x4[k * WAVE + lane];
    const int base = (k * WAVE + lane) * 4;
    const float w0 = sup[(size_t)(base + 0) * CC + lab];
    const float w1 = sup[(size_t)(base + 1) * CC + lab];
    const float w2 = sup[(size_t)(base + 2) * CC + lab];
    const float w3 = sup[(size_t)(base + 3) * CC + lab];
    amax2(xv.x, base + 0, m, mi); amax2(xv.y, base + 1, m, mi);
    amax2(xv.z, base + 2, m, mi); amax2(xv.w, base + 3, m, mi);
    se += __expf(xv.x) + __expf(xv.y) + __expf(xv.z) + __expf(xv.w);
    W  += w0 + w1 + w2 + w3;
    WX += w0 * xv.x + w1 * xv.y + w2 * xv.z + w3 * xv.w;
  }
  wave_argmax(m, mi);
  const int pred = mi;
  const float Z = wave_sum(se), Wt = wave_sum(W), WXt = wave_sum(WX);
  const float logZ = __logf(Z);
  if (pred == lab) {
    const float invZ = 1.0f / Z;
    for (int k = 0; k < K16; ++k) {
      const float4 xv = x4[k * WAVE + lane];
      const int base = (k * WAVE + lane) * 4;
      atomicAdd(&upd[(size_t)(base + 0) * CC + pred], __expf(xv.x) * invZ);
      atomicAdd(&upd[(size_t)(base + 1) * CC + pred], __expf(xv.y) * invZ);
      atomicAdd(&upd[(size_t)(base + 2) * CC + pred], __expf(xv.z) * invZ);
      atomicAdd(&upd[(size_t)(base + 3) * CC + pred], __expf(xv.w) * invZ);
    }
    if (lane == 0) atomicAdd(&cnt[pred], 1.0f);
  }
  if (lane == 0) {
    const int slot = (b & (ACC_SLOTS - 1)) * 2;
    atomicAdd(&acc[slot + 0], (double)(logZ - xl));
    atomicAdd(&acc[slot + 1], (double)(logZ * Wt - WXt));
  }
}

extern "C" void kernel_launch(void* const* d_in, const int* in_sizes, int n_in,
                              void* d_out, int out_size, void* d_ws, size_t ws_size,
                              hipStream_t stream) {
  const float* y_h = (const float*)d_in[0];
  const float* y   = (const float*)d_in[1];
  const float* sup = (const float*)d_in[2];
  const int C = CC;                       // 4096 (supervise is C*C)
  const int B = in_sizes[0] / C;          // 16384

  float* out        = (float*)d_out;
  float* out_update = out + 1;
  float* out_count  = out + 1 + (size_t)C * C;

  // ws layout: acc @0 (1KB) | labels @4096 (B*4=64KB) | supT @69632 (64MB)
  char* ws = (char*)d_ws;
  double* acc    = (double*)ws;
  int*    labels = (int*)(ws + 4096);
  float*  supT   = (float*)(ws + 4096 + 65536);
  const size_t need = 4096 + 65536 + (size_t)C * C * sizeof(float);

  if (ws_size >= need) {
    // even blocks: (C/32)^2 = 16384 transpose tiles; odd: 16384 rows
    ols_mega<<<32768, TPB, 0, stream>>>(sup, supT, out_update, out_count,
                                        acc, y, labels, C);
    ols_row<<<B, TPB, 0, stream>>>(y_h, labels, supT,
                                   out_update, out_count, acc);
    ols_finalize<<<1, 1, 0, stream>>>(acc, out, 1.0 / (double)B);
  } else {
    hipMemsetAsync(d_out, 0, (size_t)out_size * sizeof(float), stream);
    hipMemsetAsync(d_ws, 0, 4096, stream);
    ols_fallback<<<B / WPB, TPB, 0, stream>>>(y_h, y, sup,
                                              out_update, out_count, acc);
    ols_finalize<<<1, 1, 0, stream>>>(acc, out, 1.0 / (double)B);
  }
}